// Round 3
// baseline (49.217 us; speedup 1.0000x reference)
//
#include <hip/hip_runtime.h>
#include <hip/hip_bf16.h>

#define BB 16
#define FF 128
#define HH 144
#define EE 24
#define C0C 12

typedef float v4f __attribute__((ext_vector_type(4)));

// Workspace layout (floats):
//   num_t: [B][F+1][H]  (cumsum of p*d, leading zero row)
//   den_t: [B][F+1][H]  (cumsum of p,   leading zero row)
#define TABLE_ELEMS (BB * (FF + 1) * HH)

__device__ __forceinline__ float fastdiv(float n, float d) {
    float r = __builtin_amdgcn_rcpf(d);
    r = fmaf(fmaf(-d, r, 1.0f), r, r);   // one Newton iteration
    return n * r;
}

__global__ __launch_bounds__(128) void seg_k1(
    const float* __restrict__ note,   // [B][F][E]
    const float* __restrict__ hv,     // [B][H][E]
    const float* __restrict__ W0,     // [12][12]
    const float* __restrict__ b0,     // [12]
    const float* __restrict__ W1,     // [12][12]
    const float* __restrict__ b1,     // [12]
    const float* __restrict__ Wc,     // [24][24]
    const float* __restrict__ bc,     // [24]
    float* __restrict__ num_t,
    float* __restrict__ den_t)
{
    const int blk = blockIdx.x;           // b*H + h
    const int b = blk / HH;
    const int h = blk - b * HH;
    const int tid = threadIdx.x;
    const int lane = tid & 63;

    __shared__ float s_hcat[EE];
    __shared__ float s_q[EE];
    __shared__ float s_wmax[2];
    __shared__ float s_tot[2];

    const float* hvb = hv + ((size_t)b * HH + h) * EE;
    if (tid < C0C) {
        float acc = b0[tid];
        #pragma unroll
        for (int j = 0; j < C0C; ++j) acc += W0[tid * C0C + j] * hvb[j];
        s_hcat[tid] = acc;
    } else if (tid < 2 * C0C) {
        const int i = tid - C0C;
        float acc = b1[i];
        #pragma unroll
        for (int j = 0; j < C0C; ++j) acc += W1[i * C0C + j] * hvb[C0C + j];
        s_hcat[tid] = acc;
    }
    __syncthreads();
    if (tid < EE) {
        float acc = bc[tid];
        #pragma unroll
        for (int j = 0; j < EE; ++j) acc += Wc[tid * EE + j] * s_hcat[j];
        s_q[tid] = acc;
    }
    __syncthreads();

    // d_l for l = tid, note row read straight from global (L2-resident)
    const float* nr = note + ((size_t)b * FF + tid) * EE;
    float d = 0.f;
    #pragma unroll
    for (int e = 0; e < EE; e += 4) {
        const v4f v = *reinterpret_cast<const v4f*>(nr + e);
        d += s_q[e] * v.x + s_q[e + 1] * v.y + s_q[e + 2] * v.z + s_q[e + 3] * v.w;
    }

    const float scale = 0.20412414523193150818f;  // 1/sqrt(24)
    const float ds = d * scale;

    // block max over 128 threads (2 waves)
    float m = ds;
    #pragma unroll
    for (int off = 32; off > 0; off >>= 1) m = fmaxf(m, __shfl_xor(m, off));
    if (lane == 0) s_wmax[tid >> 6] = m;
    __syncthreads();
    m = fmaxf(s_wmax[0], s_wmax[1]);

    float p = __expf(ds - m);
    float pd = p * d;

    // in-wave inclusive scan (width 64), then cross-wave fixup
    #pragma unroll
    for (int off = 1; off < 64; off <<= 1) {
        const float a = __shfl_up(p, off);
        const float c = __shfl_up(pd, off);
        if (lane >= off) { p += a; pd += c; }
    }
    if (tid == 63) { s_tot[0] = p; s_tot[1] = pd; }
    __syncthreads();
    if (tid >= 64) { p += s_tot[0]; pd += s_tot[1]; }

    const size_t base = (size_t)b * (FF + 1) * HH + h;
    num_t[base + (size_t)(tid + 1) * HH] = pd;
    den_t[base + (size_t)(tid + 1) * HH] = p;
    if (tid == 0) {
        num_t[base] = 0.f;
        den_t[base] = 0.f;
    }
}

__global__ __launch_bounds__(256) void seg_k2(
    const float* __restrict__ num_t,
    const float* __restrict__ den_t,
    float* __restrict__ out)          // [B][F(s)][F(e)][H]
{
    const int blk = blockIdx.x;        // b*F + s
    const int b = blk >> 7;
    const int s = blk & 127;
    const int tid = threadIdx.x;

    __shared__ float s_n0[HH];
    __shared__ float s_d0[HH];

    const float* nb = num_t + (size_t)b * (FF + 1) * HH;
    const float* db = den_t + (size_t)b * (FF + 1) * HH;
    if (tid < HH) {
        s_n0[tid] = nb[(size_t)s * HH + tid];
        s_d0[tid] = db[(size_t)s * HH + tid];
    }
    __syncthreads();

    float* ob = out + (size_t)blk * (FF * HH);

    // 4608 float4 chunks per (b,s) row; stride 256 chunks = 1024 elems = 7*144+16
    int i = tid * 4;
    int e = i / HH;
    int h = i - e * HH;
    #pragma unroll 2
    for (int it = 0; it < (FF * HH / 4) / 256; ++it) {   // 18 iterations
        v4f val = (v4f)(0.f);
        if (e >= s) {
            const v4f n1 = *reinterpret_cast<const v4f*>(nb + (size_t)(e + 1) * HH + h);
            const v4f d1 = *reinterpret_cast<const v4f*>(db + (size_t)(e + 1) * HH + h);
            const v4f n0 = *reinterpret_cast<const v4f*>(&s_n0[h]);
            const v4f d0 = *reinterpret_cast<const v4f*>(&s_d0[h]);
            val.x = fastdiv(n1.x - n0.x, d1.x - d0.x);
            val.y = fastdiv(n1.y - n0.y, d1.y - d0.y);
            val.z = fastdiv(n1.z - n0.z, d1.z - d0.z);
            val.w = fastdiv(n1.w - n0.w, d1.w - d0.w);
        }
        __builtin_nontemporal_store(val, reinterpret_cast<v4f*>(ob + i));
        i += 1024;
        e += 7;
        h += 16;
        if (h >= HH) { h -= HH; ++e; }
    }
}

extern "C" void kernel_launch(void* const* d_in, const int* in_sizes, int n_in,
                              void* d_out, int out_size, void* d_ws, size_t ws_size,
                              hipStream_t stream) {
    const float* note = (const float*)d_in[0];
    const float* hv   = (const float*)d_in[1];
    const float* W0   = (const float*)d_in[2];
    const float* b0   = (const float*)d_in[3];
    const float* W1   = (const float*)d_in[4];
    const float* b1   = (const float*)d_in[5];
    const float* Wc   = (const float*)d_in[6];
    const float* bc   = (const float*)d_in[7];
    float* out = (float*)d_out;

    float* num_t = (float*)d_ws;
    float* den_t = num_t + TABLE_ELEMS;

    seg_k1<<<BB * HH, 128, 0, stream>>>(note, hv, W0, b0, W1, b1, Wc, bc, num_t, den_t);
    seg_k2<<<BB * FF, 256, 0, stream>>>(num_t, den_t, out);
}

// Round 4
// 41.826 us; speedup vs baseline: 1.1767x; 1.1767x over previous
//
#include <hip/hip_runtime.h>
#include <hip/hip_bf16.h>

#define BB 16
#define FF 128
#define HH 144
#define EE 24
#define C0C 12

typedef float v4f __attribute__((ext_vector_type(4)));

// Workspace layout (floats):
//   num_t: [B][F+1][H]  (cumsum of p*d, leading zero row)
//   den_t: [B][F+1][H]  (cumsum of p,   leading zero row)
#define TABLE_ELEMS (BB * (FF + 1) * HH)

__device__ __forceinline__ float fastdiv(float n, float d) {
    float r = __builtin_amdgcn_rcpf(d);
    r = fmaf(fmaf(-d, r, 1.0f), r, r);   // one Newton iteration
    return n * r;
}

__global__ __launch_bounds__(128) void seg_k1(
    const float* __restrict__ note,   // [B][F][E]
    const float* __restrict__ hv,     // [B][H][E]
    const float* __restrict__ W0,     // [12][12]
    const float* __restrict__ b0,     // [12]
    const float* __restrict__ W1,     // [12][12]
    const float* __restrict__ b1,     // [12]
    const float* __restrict__ Wc,     // [24][24]
    const float* __restrict__ bc,     // [24]
    float* __restrict__ num_t,
    float* __restrict__ den_t)
{
    const int blk = blockIdx.x;           // b*H + h
    const int b = blk / HH;
    const int h = blk - b * HH;
    const int tid = threadIdx.x;
    const int lane = tid & 63;

    __shared__ float s_hcat[EE];
    __shared__ float s_q[EE];
    __shared__ float s_wmax[2];
    __shared__ float s_tot[2];

    const float* hvb = hv + ((size_t)b * HH + h) * EE;
    if (tid < C0C) {
        float acc = b0[tid];
        #pragma unroll
        for (int j = 0; j < C0C; ++j) acc += W0[tid * C0C + j] * hvb[j];
        s_hcat[tid] = acc;
    } else if (tid < 2 * C0C) {
        const int i = tid - C0C;
        float acc = b1[i];
        #pragma unroll
        for (int j = 0; j < C0C; ++j) acc += W1[i * C0C + j] * hvb[C0C + j];
        s_hcat[tid] = acc;
    }
    __syncthreads();
    if (tid < EE) {
        float acc = bc[tid];
        #pragma unroll
        for (int j = 0; j < EE; ++j) acc += Wc[tid * EE + j] * s_hcat[j];
        s_q[tid] = acc;
    }
    __syncthreads();

    // d_l for l = tid, note row read straight from global (L2-resident)
    const float* nr = note + ((size_t)b * FF + tid) * EE;
    float d = 0.f;
    #pragma unroll
    for (int e = 0; e < EE; e += 4) {
        const v4f v = *reinterpret_cast<const v4f*>(nr + e);
        d += s_q[e] * v.x + s_q[e + 1] * v.y + s_q[e + 2] * v.z + s_q[e + 3] * v.w;
    }

    const float scale = 0.20412414523193150818f;  // 1/sqrt(24)
    const float ds = d * scale;

    // block max over 128 threads (2 waves)
    float m = ds;
    #pragma unroll
    for (int off = 32; off > 0; off >>= 1) m = fmaxf(m, __shfl_xor(m, off));
    if (lane == 0) s_wmax[tid >> 6] = m;
    __syncthreads();
    m = fmaxf(s_wmax[0], s_wmax[1]);

    float p = __expf(ds - m);
    float pd = p * d;

    // in-wave inclusive scan (width 64), then cross-wave fixup
    #pragma unroll
    for (int off = 1; off < 64; off <<= 1) {
        const float a = __shfl_up(p, off);
        const float c = __shfl_up(pd, off);
        if (lane >= off) { p += a; pd += c; }
    }
    if (tid == 63) { s_tot[0] = p; s_tot[1] = pd; }
    __syncthreads();
    if (tid >= 64) { p += s_tot[0]; pd += s_tot[1]; }

    const size_t base = (size_t)b * (FF + 1) * HH + h;
    num_t[base + (size_t)(tid + 1) * HH] = pd;
    den_t[base + (size_t)(tid + 1) * HH] = p;
    if (tid == 0) {
        num_t[base] = 0.f;
        den_t[base] = 0.f;
    }
}

__global__ __launch_bounds__(256) void seg_k2(
    const float* __restrict__ num_t,
    const float* __restrict__ den_t,
    float* __restrict__ out)          // [B][F(s)][F(e)][H]
{
    const int blk = blockIdx.x;        // b*F + s
    const int b = blk >> 7;
    const int s = blk & 127;
    const int tid = threadIdx.x;

    const float* nb = num_t + (size_t)b * (FF + 1) * HH;
    const float* db = den_t + (size_t)b * (FF + 1) * HH;
    float* ob = out + (size_t)blk * (FF * HH);

    // ---- Phase A: rows e in [0, s) are zero. Pure coalesced stores. ----
    const int nz4 = s * (HH / 4);                 // float4 chunks to zero
    for (int c = tid; c < nz4; c += 256) {
        *reinterpret_cast<v4f*>(ob + (size_t)c * 4) = (v4f)(0.f);
    }

    // ---- Phase B: rows e in [s, 128). tid -> (r, c), fixed h = 4c. ----
    if (tid < 252) {
        const int r = tid / 36;                   // 0..6  (row offset)
        const int c = tid - r * 36;               // 0..35 (16B chunk in row)
        const int h = c * 4;

        const v4f n0 = *reinterpret_cast<const v4f*>(nb + (size_t)s * HH + h);
        const v4f d0 = *reinterpret_cast<const v4f*>(db + (size_t)s * HH + h);

        const float* pn = nb + (size_t)(s + r + 1) * HH + h;
        const float* pd_ = db + (size_t)(s + r + 1) * HH + h;
        float* po = ob + (size_t)(s + r) * HH + h;

        for (int e = s + r; e < FF; e += 7) {
            const v4f n1 = *reinterpret_cast<const v4f*>(pn);
            const v4f d1 = *reinterpret_cast<const v4f*>(pd_);
            v4f val;
            val.x = fastdiv(n1.x - n0.x, d1.x - d0.x);
            val.y = fastdiv(n1.y - n0.y, d1.y - d0.y);
            val.z = fastdiv(n1.z - n0.z, d1.z - d0.z);
            val.w = fastdiv(n1.w - n0.w, d1.w - d0.w);
            *reinterpret_cast<v4f*>(po) = val;
            pn += 7 * HH;
            pd_ += 7 * HH;
            po += 7 * HH;
        }
    }
}

extern "C" void kernel_launch(void* const* d_in, const int* in_sizes, int n_in,
                              void* d_out, int out_size, void* d_ws, size_t ws_size,
                              hipStream_t stream) {
    const float* note = (const float*)d_in[0];
    const float* hv   = (const float*)d_in[1];
    const float* W0   = (const float*)d_in[2];
    const float* b0   = (const float*)d_in[3];
    const float* W1   = (const float*)d_in[4];
    const float* b1   = (const float*)d_in[5];
    const float* Wc   = (const float*)d_in[6];
    const float* bc   = (const float*)d_in[7];
    float* out = (float*)d_out;

    float* num_t = (float*)d_ws;
    float* den_t = num_t + TABLE_ELEMS;

    seg_k1<<<BB * HH, 128, 0, stream>>>(note, hv, W0, b0, W1, b1, Wc, bc, num_t, den_t);
    seg_k2<<<BB * FF, 256, 0, stream>>>(num_t, den_t, out);
}